// Round 11
// baseline (49.521 us; speedup 1.0000x reference)
//
#include <hip/hip_runtime.h>
#include <math.h>

#define H 2048
#define L 350
#define NB 1024
#define NLOGB 88            // blocks 0..87: logits first
#define NMAIN 872           // blocks 88..959: gh bulk
#define CTX0  960           // blocks 960..1023: ctx (64)
#define NCTXB 64

// gh row partition
#define GH_MAIN 5448        // rows [0,5448): main blocks, stride 872
#define GH_LOG  5888        // rows [5448,5888): logit blocks, stride 88 (5 ea)
                            // rows [5888,6144): ctx blocks, stride 64 (4 ea)

// ws float offsets
#define OFF_GH   512
#define OFF_G    7168
#define OFF_CTX  9216
#define OFF_CNT  12288      // 4 groups x 1024 uints (4KB each) = 16 KB

#define GRP_LOG 0
#define GRP_CTX 1
#define GRP_GH  2
#define GRP_CMB 3

#define VMCNT0() asm volatile("s_waitcnt vmcnt(0)" ::: "memory")

__device__ __forceinline__ float cload(const float* p) {
    return __hip_atomic_load(p, __ATOMIC_RELAXED, __HIP_MEMORY_SCOPE_AGENT);
}
__device__ __forceinline__ void cstore(float* p, float v) {
    __hip_atomic_store(p, v, __ATOMIC_RELAXED, __HIP_MEMORY_SCOPE_AGENT);
}
__device__ __forceinline__ unsigned long long cload64(const unsigned long long* p) {
    return __hip_atomic_load(p, __ATOMIC_RELAXED, __HIP_MEMORY_SCOPE_AGENT);
}
__device__ __forceinline__ void post(unsigned* grp_base, int b) {
    __hip_atomic_fetch_add(&grp_base[(b & 31) * 16], 1u,
                           __ATOMIC_RELAXED, __HIP_MEMORY_SCOPE_SYSTEM);
}
__device__ __forceinline__ unsigned peek(const unsigned* p) {
    return __hip_atomic_load(p, __ATOMIC_RELAXED, __HIP_MEMORY_SCOPE_SYSTEM);
}

__device__ __forceinline__ float dot4(float4 a, float4 b, float acc) {
    acc = fmaf(a.x, b.x, acc);
    acc = fmaf(a.y, b.y, acc);
    acc = fmaf(a.z, b.z, acc);
    acc = fmaf(a.w, b.w, acc);
    return acc;
}
__device__ __forceinline__ float wsum(float v) {
    #pragma unroll
    for (int m = 1; m < 64; m <<= 1) v += __shfl_xor(v, m, 64);
    return v;
}
__device__ __forceinline__ float wmax(float v) {
    #pragma unroll
    for (int m = 1; m < 64; m <<= 1) v = fmaxf(v, __shfl_xor(v, m, 64));
    return v;
}
__device__ __forceinline__ unsigned wsumu(unsigned v) {
    #pragma unroll
    for (int m = 1; m < 64; m <<= 1) v += (unsigned)__shfl_xor((int)v, m, 64);
    return v;
}

// block-level wait: sum of 32 padded sub-counters >= target. Bounded: fails fast.
__device__ __forceinline__ void waitgrp(unsigned* grp_base, unsigned target) {
    __syncthreads();
    if (threadIdx.x < 64) {
        for (int it = 0; it < (1 << 20); ++it) {
            unsigned v = (threadIdx.x < 32) ? peek(&grp_base[threadIdx.x * 16]) : 0u;
            v = wsumu(v);
            if (v >= target) break;
            __builtin_amdgcn_s_sleep(2);
        }
    }
    __syncthreads();
}

__device__ __forceinline__ void gh_row(int r, int lane,
    const float4* h4, const float* w_hh, const float* b_hh, float* gh)
{
    const float4* Wr = reinterpret_cast<const float4*>(w_hh + (size_t)r * H);
    float acc = 0.f;
    #pragma unroll
    for (int i = lane; i < H / 4; i += 64) acc = dot4(Wr[i], h4[i], acc);
    acc = wsum(acc);
    if (lane == 0) cstore(&gh[r], acc + b_hh[r]);
}

__global__ __launch_bounds__(256, 4) void fused_decoder(
    const float* __restrict__ input, const float* __restrict__ hidden,
    const float* __restrict__ enc,
    const float* __restrict__ attn_W, const float* __restrict__ attn_b,
    const float* __restrict__ comb_W, const float* __restrict__ comb_b,
    const float* __restrict__ w_ih, const float* __restrict__ w_hh,
    const float* __restrict__ b_ih, const float* __restrict__ b_hh,
    float* __restrict__ out, float* __restrict__ ws)
{
    __shared__ __align__(16) float sh[2048];
    __shared__ float smax[4], ssum[4];
    __shared__ float part[8][32];
    __shared__ float red[4];
    __shared__ float p3[4][3];

    float* logits = ws;
    float* gh     = ws + OFF_GH;
    float* g      = ws + OFF_G;
    float* ctx    = ws + OFF_CTX;
    unsigned* cnt = (unsigned*)(ws + OFF_CNT);
    unsigned* cLOG = cnt + GRP_LOG * 1024;
    unsigned* cCTX = cnt + GRP_CTX * 1024;
    unsigned* cGH  = cnt + GRP_GH  * 1024;
    unsigned* cCMB = cnt + GRP_CMB * 1024;

    const int b = blockIdx.x, tid = threadIdx.x;
    const int wv = tid >> 6, lane = tid & 63;
    const float4* x4 = reinterpret_cast<const float4*>(input);
    const float4* h4 = reinterpret_cast<const float4*>(hidden);

    if (b < NLOGB) {
        // ---- logits (critical path first): 1 row/wave ----
        const int r = b * 4 + wv;
        if (r < L) {
            const float4* Wr = reinterpret_cast<const float4*>(attn_W + (size_t)r * (2 * H));
            float acc = 0.f;
            #pragma unroll
            for (int i = lane; i < H / 4; i += 64) {
                acc = dot4(Wr[i], x4[i], acc);
                acc = dot4(Wr[H / 4 + i], h4[i], acc);
            }
            acc = wsum(acc);
            if (lane == 0) cstore(&logits[r], acc + attn_b[r]);
        }
        VMCNT0();
        __syncthreads();
        if (tid == 0) post(cLOG, b);
        // ---- gh share: 5 rows ----
        int idx = 0;
        for (int r2 = GH_MAIN + b; r2 < GH_LOG; r2 += NLOGB, ++idx)
            if ((idx & 3) == wv) gh_row(r2, lane, h4, w_hh, b_hh, gh);
        VMCNT0();
        __syncthreads();
        if (tid == 0) post(cGH, b);
    } else if (b < CTX0) {
        // ---- gh bulk: 6-7 rows ----
        const int m = b - NLOGB;
        int idx = 0;
        for (int r2 = m; r2 < GH_MAIN; r2 += NMAIN, ++idx)
            if ((idx & 3) == wv) gh_row(r2, lane, h4, w_hh, b_hh, gh);
        VMCNT0();
        __syncthreads();
        if (tid == 0) post(cGH, b);
    } else {
        // ---- ctx blocks: gh share (1 row/wave), then softmax + 32 ctx cols
        const int c = b - CTX0;
        gh_row(GH_LOG + c + wv * NCTXB, lane, h4, w_hh, b_hh, gh);
        VMCNT0();
        __syncthreads();
        if (tid == 0) post(cGH, b);

        waitgrp(cLOG, NLOGB);
        float v0 = (tid < L) ? cload(&logits[tid]) : -INFINITY;
        float v1 = (tid + 256 < L) ? cload(&logits[tid + 256]) : -INFINITY;
        float m = wmax(fmaxf(v0, v1));
        if (lane == 0) smax[wv] = m;
        __syncthreads();
        m = fmaxf(fmaxf(smax[0], smax[1]), fmaxf(smax[2], smax[3]));
        float e0 = (tid < L) ? expf(v0 - m) : 0.f;
        float e1 = (tid + 256 < L) ? expf(v1 - m) : 0.f;
        float s = wsum(e0 + e1);
        if (lane == 0) ssum[wv] = s;
        __syncthreads();
        const float inv = 1.f / (ssum[0] + ssum[1] + ssum[2] + ssum[3]);
        if (tid < L) sh[tid] = e0 * inv;
        if (tid + 256 < L) sh[tid + 256] = e1 * inv;
        if (c == 0) {
            if (tid < L) out[2 * H + tid] = e0 * inv;
            if (tid + 256 < L) out[2 * H + tid + 256] = e1 * inv;
        }
        __syncthreads();
        const int col_l = tid & 31, k = tid >> 5;
        const float* ec = enc + c * 32 + col_l;
        float a0 = 0.f, a1 = 0.f, a2 = 0.f, a3 = 0.f;
        int j = k;
        for (; j + 24 < L; j += 32) {
            a0 = fmaf(sh[j],      ec[(size_t)j * H],        a0);
            a1 = fmaf(sh[j + 8],  ec[(size_t)(j + 8) * H],  a1);
            a2 = fmaf(sh[j + 16], ec[(size_t)(j + 16) * H], a2);
            a3 = fmaf(sh[j + 24], ec[(size_t)(j + 24) * H], a3);
        }
        for (; j < L; j += 8) a0 = fmaf(sh[j], ec[(size_t)j * H], a0);
        part[k][col_l] = (a0 + a1) + (a2 + a3);
        __syncthreads();
        if (tid < 32) {
            float acc = 0.f;
            #pragma unroll
            for (int kk = 0; kk < 8; ++kk) acc += part[kk][tid];
            cstore(&ctx[c * 32 + tid], acc);
        }
        VMCNT0();
        __syncthreads();
        if (tid == 0) post(cCTX, b);
    }

    // ================= combine: wait ctx, stage to LDS, 2 rows/block =======
    waitgrp(cCTX, NCTXB);
    {
        unsigned long long* sh64 = reinterpret_cast<unsigned long long*>(sh);
        const unsigned long long* c64 = reinterpret_cast<const unsigned long long*>(ctx);
        for (int i = tid; i < H / 2; i += 256) sh64[i] = cload64(&c64[i]);
    }
    __syncthreads();
    {
        const float4* c4 = reinterpret_cast<const float4*>(sh);
        #pragma unroll
        for (int rr = 0; rr < 2; ++rr) {
            const int r = b * 2 + rr;
            const float4* Wr = reinterpret_cast<const float4*>(comb_W + (size_t)r * (2 * H));
            float acc = dot4(Wr[tid], x4[tid], 0.f);
            acc = dot4(Wr[tid + 256], x4[tid + 256], acc);
            acc = dot4(Wr[tid + 512], c4[tid], acc);
            acc = dot4(Wr[tid + 768], c4[tid + 256], acc);
            acc = wsum(acc);
            if (lane == 0) red[wv] = acc;
            __syncthreads();
            if (tid == 0)
                cstore(&g[r], fmaxf(red[0] + red[1] + red[2] + red[3] + comb_b[r], 0.f));
            __syncthreads();
        }
    }
    VMCNT0();
    if (tid == 0) post(cCMB, b);

    // ================= GRU: wait gh+cmb, stage g to LDS, 2 cols/block ======
    waitgrp(cGH, NB);
    waitgrp(cCMB, NB);
    {
        unsigned long long* sh64 = reinterpret_cast<unsigned long long*>(sh);
        const unsigned long long* g64 = reinterpret_cast<const unsigned long long*>(g);
        for (int i = tid; i < H / 2; i += 256) sh64[i] = cload64(&g64[i]);
    }
    __syncthreads();
    {
        const float4* g4 = reinterpret_cast<const float4*>(sh);
        #pragma unroll
        for (int cc = 0; cc < 2; ++cc) {
            const int col = b * 2 + cc;
            const float4* W0 = reinterpret_cast<const float4*>(w_ih + (size_t)col * H);
            const float4* W1 = reinterpret_cast<const float4*>(w_ih + (size_t)(col + H) * H);
            const float4* W2 = reinterpret_cast<const float4*>(w_ih + (size_t)(col + 2 * H) * H);
            const float4 gv0 = g4[tid], gv1 = g4[tid + 256];
            float ar = dot4(W0[tid], gv0, 0.f); ar = dot4(W0[tid + 256], gv1, ar);
            float az = dot4(W1[tid], gv0, 0.f); az = dot4(W1[tid + 256], gv1, az);
            float an = dot4(W2[tid], gv0, 0.f); an = dot4(W2[tid + 256], gv1, an);
            ar = wsum(ar); az = wsum(az); an = wsum(an);
            if (lane == 0) { p3[wv][0] = ar; p3[wv][1] = az; p3[wv][2] = an; }
            __syncthreads();
            if (tid == 0) {
                const float ir  = p3[0][0] + p3[1][0] + p3[2][0] + p3[3][0] + b_ih[col];
                const float iz  = p3[0][1] + p3[1][1] + p3[2][1] + p3[3][1] + b_ih[col + H];
                const float in_ = p3[0][2] + p3[1][2] + p3[2][2] + p3[3][2] + b_ih[col + 2 * H];
                const float r = 1.f / (1.f + expf(-(ir + cload(&gh[col]))));
                const float z = 1.f / (1.f + expf(-(iz + cload(&gh[col + H]))));
                const float n = tanhf(in_ + r * cload(&gh[col + 2 * H]));
                const float hnew = (1.f - z) * n + z * hidden[col];
                out[col] = hnew;
                out[H + col] = hnew;
            }
            __syncthreads();
        }
    }
}

extern "C" void kernel_launch(void* const* d_in, const int* in_sizes, int n_in,
                              void* d_out, int out_size, void* d_ws, size_t ws_size,
                              hipStream_t stream)
{
    const float* input  = (const float*)d_in[0];
    const float* hidden = (const float*)d_in[1];
    const float* enc    = (const float*)d_in[2];
    const float* attn_W = (const float*)d_in[3];
    const float* attn_b = (const float*)d_in[4];
    const float* comb_W = (const float*)d_in[5];
    const float* comb_b = (const float*)d_in[6];
    const float* w_ih   = (const float*)d_in[7];
    const float* w_hh   = (const float*)d_in[8];
    const float* b_ih   = (const float*)d_in[9];
    const float* b_hh   = (const float*)d_in[10];
    float* out = (float*)d_out;
    float* ws  = (float*)d_ws;

    // 4 counter groups x 4 KB must start zeroed
    hipMemsetAsync(ws + OFF_CNT, 0, 16384, stream);

    fused_decoder<<<NB, 256, 0, stream>>>(
        input, hidden, enc, attn_W, attn_b, comb_W, comb_b,
        w_ih, w_hh, b_ih, b_hh, out, ws);
}

// Round 12
// 45.544 us; speedup vs baseline: 1.0873x; 1.0873x over previous
//
#include <hip/hip_runtime.h>
#include <math.h>

#define H 2048
#define L 350
#define NB 1024
#define NLOGB 88            // blocks 0..87: logits first
#define NMAIN 872           // blocks 88..959: gh bulk
#define CTX0  960           // blocks 960..1023: ctx (64)
#define NCTXB 64
#define NREP 8              // ctx/g replication factor

// gh row partition
#define GH_MAIN 5448        // rows [0,5448): main blocks
#define GH_LOG  5888        // rows [5448,5888): logit blocks (5 ea)
                            // rows [5888,6144): ctx blocks (4 ea)

// ws float offsets
#define OFF_GH   512                  // 512..6656
#define OFF_G    8192                 // 8 replicas x 2048
#define OFF_CTX  24576                // 8 replicas x 2048
#define OFF_CNT  40960                // 4 groups x 1024 uints + flags

#define GRP_LOG 0
#define GRP_CTX 1
#define GRP_GH  2
#define GRP_CMB 3

#define VMCNT0() asm volatile("s_waitcnt vmcnt(0)" ::: "memory")

__device__ __forceinline__ float cload(const float* p) {
    return __hip_atomic_load(p, __ATOMIC_RELAXED, __HIP_MEMORY_SCOPE_AGENT);
}
__device__ __forceinline__ void cstore(float* p, float v) {
    __hip_atomic_store(p, v, __ATOMIC_RELAXED, __HIP_MEMORY_SCOPE_AGENT);
}
__device__ __forceinline__ unsigned long long cload64(const unsigned long long* p) {
    return __hip_atomic_load(p, __ATOMIC_RELAXED, __HIP_MEMORY_SCOPE_AGENT);
}
__device__ __forceinline__ void post(unsigned* grp_base, int b) {
    __hip_atomic_fetch_add(&grp_base[(b & 31) * 16], 1u,
                           __ATOMIC_RELAXED, __HIP_MEMORY_SCOPE_SYSTEM);
}
__device__ __forceinline__ unsigned peek(const unsigned* p) {
    return __hip_atomic_load(p, __ATOMIC_RELAXED, __HIP_MEMORY_SCOPE_SYSTEM);
}
__device__ __forceinline__ void sysset(unsigned* p) {
    __hip_atomic_store(p, 1u, __ATOMIC_RELAXED, __HIP_MEMORY_SCOPE_SYSTEM);
}

__device__ __forceinline__ float dot4(float4 a, float4 b, float acc) {
    acc = fmaf(a.x, b.x, acc);
    acc = fmaf(a.y, b.y, acc);
    acc = fmaf(a.z, b.z, acc);
    acc = fmaf(a.w, b.w, acc);
    return acc;
}
__device__ __forceinline__ float wsum(float v) {
    #pragma unroll
    for (int m = 1; m < 64; m <<= 1) v += __shfl_xor(v, m, 64);
    return v;
}
__device__ __forceinline__ float wmax(float v) {
    #pragma unroll
    for (int m = 1; m < 64; m <<= 1) v = fmaxf(v, __shfl_xor(v, m, 64));
    return v;
}
__device__ __forceinline__ unsigned wsumu(unsigned v) {
    #pragma unroll
    for (int m = 1; m < 64; m <<= 1) v += (unsigned)__shfl_xor((int)v, m, 64);
    return v;
}

// aggregator-side: sum 32 sub-counters until >= target (bounded)
__device__ __forceinline__ void agg_wait(unsigned* grp, unsigned target, int tid) {
    if (tid < 64) {
        for (int it = 0; it < (1 << 20); ++it) {
            unsigned v = (tid < 32) ? peek(&grp[tid * 16]) : 0u;
            v = wsumu(v);
            if (v >= target) break;
            __builtin_amdgcn_s_sleep(2);
        }
    }
    __syncthreads();
}
// consumer-side: poll one flag line (bounded)
__device__ __forceinline__ void flag_wait(unsigned* f, int tid) {
    __syncthreads();
    if (tid == 0) {
        for (int it = 0; it < (1 << 20); ++it) {
            if (peek(f)) break;
            __builtin_amdgcn_s_sleep(16);
        }
    }
    __syncthreads();
}

__device__ __forceinline__ void gh_row(int r, int lane,
    const float4* h4, const float* w_hh, const float* b_hh, float* gh)
{
    const float4* Wr = reinterpret_cast<const float4*>(w_hh + (size_t)r * H);
    float acc = 0.f;
    #pragma unroll
    for (int i = lane; i < H / 4; i += 64) acc = dot4(Wr[i], h4[i], acc);
    acc = wsum(acc);
    if (lane == 0) cstore(&gh[r], acc + b_hh[r]);
}

__global__ __launch_bounds__(256, 4) void fused_decoder(
    const float* __restrict__ input, const float* __restrict__ hidden,
    const float* __restrict__ enc,
    const float* __restrict__ attn_W, const float* __restrict__ attn_b,
    const float* __restrict__ comb_W, const float* __restrict__ comb_b,
    const float* __restrict__ w_ih, const float* __restrict__ w_hh,
    const float* __restrict__ b_ih, const float* __restrict__ b_hh,
    float* __restrict__ out, float* __restrict__ ws)
{
    __shared__ __align__(16) float sh[2048];
    __shared__ float smax[4], ssum[4];
    __shared__ float part[8][32];
    __shared__ float red[4];
    __shared__ float p3[4][3];

    float* logits = ws;
    float* gh     = ws + OFF_GH;
    float* grep   = ws + OFF_G;
    float* ctxrep = ws + OFF_CTX;
    unsigned* cnt = (unsigned*)(ws + OFF_CNT);
    unsigned* cLOG = cnt + GRP_LOG * 1024;
    unsigned* cCTX = cnt + GRP_CTX * 1024;
    unsigned* cGH  = cnt + GRP_GH  * 1024;
    unsigned* cCMB = cnt + GRP_CMB * 1024;
    unsigned* flag0 = cnt + 4096;        // ctx done
    unsigned* flag1 = cnt + 4096 + 64;   // gh+cmb done

    const int b = blockIdx.x, tid = threadIdx.x;
    const int wv = tid >> 6, lane = tid & 63;
    const float4* x4 = reinterpret_cast<const float4*>(input);
    const float4* h4 = reinterpret_cast<const float4*>(hidden);

    // ======================= phase 1 =======================
    if (b < NLOGB) {
        const int r = b * 4 + wv;
        if (r < L) {
            const float4* Wr = reinterpret_cast<const float4*>(attn_W + (size_t)r * (2 * H));
            float acc = 0.f;
            #pragma unroll
            for (int i = lane; i < H / 4; i += 64) {
                acc = dot4(Wr[i], x4[i], acc);
                acc = dot4(Wr[H / 4 + i], h4[i], acc);
            }
            acc = wsum(acc);
            if (lane == 0) cstore(&logits[r], acc + attn_b[r]);
        }
        VMCNT0();
        __syncthreads();
        if (tid == 0) post(cLOG, b);
        int idx = 0;
        for (int r2 = GH_MAIN + b; r2 < GH_LOG; r2 += NLOGB, ++idx)
            if ((idx & 3) == wv) gh_row(r2, lane, h4, w_hh, b_hh, gh);
        VMCNT0();
        __syncthreads();
        if (tid == 0) post(cGH, b);
    } else if (b < CTX0) {
        const int m = b - NLOGB;
        int idx = 0;
        for (int r2 = m; r2 < GH_MAIN; r2 += NMAIN, ++idx)
            if ((idx & 3) == wv) gh_row(r2, lane, h4, w_hh, b_hh, gh);
        VMCNT0();
        __syncthreads();
        if (tid == 0) post(cGH, b);
    } else {
        const int c = b - CTX0;
        gh_row(GH_LOG + c + wv * NCTXB, lane, h4, w_hh, b_hh, gh);
        VMCNT0();
        __syncthreads();
        if (tid == 0) post(cGH, b);

        agg_wait(cLOG, NLOGB, tid);      // 64 pollers, fine directly
        float v0 = (tid < L) ? cload(&logits[tid]) : -INFINITY;
        float v1 = (tid + 256 < L) ? cload(&logits[tid + 256]) : -INFINITY;
        float m = wmax(fmaxf(v0, v1));
        if (lane == 0) smax[wv] = m;
        __syncthreads();
        m = fmaxf(fmaxf(smax[0], smax[1]), fmaxf(smax[2], smax[3]));
        float e0 = (tid < L) ? expf(v0 - m) : 0.f;
        float e1 = (tid + 256 < L) ? expf(v1 - m) : 0.f;
        float s = wsum(e0 + e1);
        if (lane == 0) ssum[wv] = s;
        __syncthreads();
        const float inv = 1.f / (ssum[0] + ssum[1] + ssum[2] + ssum[3]);
        if (tid < L) sh[tid] = e0 * inv;
        if (tid + 256 < L) sh[tid + 256] = e1 * inv;
        if (c == 0) {
            if (tid < L) out[2 * H + tid] = e0 * inv;
            if (tid + 256 < L) out[2 * H + tid + 256] = e1 * inv;
        }
        __syncthreads();
        const int col_l = tid & 31, k = tid >> 5;
        const float* ec = enc + c * 32 + col_l;
        float a0 = 0.f, a1 = 0.f, a2 = 0.f, a3 = 0.f;
        int j = k;
        for (; j + 24 < L; j += 32) {
            a0 = fmaf(sh[j],      ec[(size_t)j * H],        a0);
            a1 = fmaf(sh[j + 8],  ec[(size_t)(j + 8) * H],  a1);
            a2 = fmaf(sh[j + 16], ec[(size_t)(j + 16) * H], a2);
            a3 = fmaf(sh[j + 24], ec[(size_t)(j + 24) * H], a3);
        }
        for (; j < L; j += 8) a0 = fmaf(sh[j], ec[(size_t)j * H], a0);
        part[k][col_l] = (a0 + a1) + (a2 + a3);
        __syncthreads();
        if (tid < 32) {
            const float acc = part[0][tid] + part[1][tid] + part[2][tid] + part[3][tid]
                            + part[4][tid] + part[5][tid] + part[6][tid] + part[7][tid];
            #pragma unroll
            for (int rp = 0; rp < NREP; ++rp)
                cstore(&ctxrep[rp * 2048 + c * 32 + tid], acc);
        }
        VMCNT0();
        __syncthreads();
        if (tid == 0) post(cCTX, b);
    }

    // ======================= barrier 1: ctx done =======================
    if (b == 0) {
        agg_wait(cCTX, NCTXB, tid);
        if (tid == 0) sysset(flag0);
    } else {
        flag_wait(flag0, tid);
    }

    // ======================= combine: 2 rows/block =======================
    {
        unsigned long long* sh64 = reinterpret_cast<unsigned long long*>(sh);
        const unsigned long long* c64 =
            reinterpret_cast<const unsigned long long*>(ctxrep + (b & (NREP - 1)) * 2048);
        for (int i = tid; i < H / 2; i += 256) sh64[i] = cload64(&c64[i]);
    }
    __syncthreads();
    {
        const float4* c4 = reinterpret_cast<const float4*>(sh);
        #pragma unroll
        for (int rr = 0; rr < 2; ++rr) {
            const int r = b * 2 + rr;
            const float4* Wr = reinterpret_cast<const float4*>(comb_W + (size_t)r * (2 * H));
            float acc = dot4(Wr[tid], x4[tid], 0.f);
            acc = dot4(Wr[tid + 256], x4[tid + 256], acc);
            acc = dot4(Wr[tid + 512], c4[tid], acc);
            acc = dot4(Wr[tid + 768], c4[tid + 256], acc);
            acc = wsum(acc);
            if (lane == 0) red[wv] = acc;
            __syncthreads();
            if (tid == 0) {
                const float gv = fmaxf(red[0] + red[1] + red[2] + red[3] + comb_b[r], 0.f);
                #pragma unroll
                for (int rp = 0; rp < NREP; ++rp) cstore(&grep[rp * 2048 + r], gv);
            }
            __syncthreads();
        }
    }
    VMCNT0();
    if (tid == 0) post(cCMB, b);

    // ======================= barrier 2: gh + cmb done =======================
    if (b == 0) {
        agg_wait(cGH, NB, tid);
        agg_wait(cCMB, NB, tid);
        if (tid == 0) sysset(flag1);
    } else {
        flag_wait(flag1, tid);
    }

    // ======================= GRU: 2 cols/block =======================
    {
        unsigned long long* sh64 = reinterpret_cast<unsigned long long*>(sh);
        const unsigned long long* g64 =
            reinterpret_cast<const unsigned long long*>(grep + (b & (NREP - 1)) * 2048);
        for (int i = tid; i < H / 2; i += 256) sh64[i] = cload64(&g64[i]);
    }
    __syncthreads();
    {
        const float4* g4 = reinterpret_cast<const float4*>(sh);
        #pragma unroll
        for (int cc = 0; cc < 2; ++cc) {
            const int col = b * 2 + cc;
            const float4* W0 = reinterpret_cast<const float4*>(w_ih + (size_t)col * H);
            const float4* W1 = reinterpret_cast<const float4*>(w_ih + (size_t)(col + H) * H);
            const float4* W2 = reinterpret_cast<const float4*>(w_ih + (size_t)(col + 2 * H) * H);
            const float4 gv0 = g4[tid], gv1 = g4[tid + 256];
            float ar = dot4(W0[tid], gv0, 0.f); ar = dot4(W0[tid + 256], gv1, ar);
            float az = dot4(W1[tid], gv0, 0.f); az = dot4(W1[tid + 256], gv1, az);
            float an = dot4(W2[tid], gv0, 0.f); an = dot4(W2[tid + 256], gv1, an);
            ar = wsum(ar); az = wsum(az); an = wsum(an);
            if (lane == 0) { p3[wv][0] = ar; p3[wv][1] = az; p3[wv][2] = an; }
            __syncthreads();
            if (tid == 0) {
                const float ir  = p3[0][0] + p3[1][0] + p3[2][0] + p3[3][0] + b_ih[col];
                const float iz  = p3[0][1] + p3[1][1] + p3[2][1] + p3[3][1] + b_ih[col + H];
                const float in_ = p3[0][2] + p3[1][2] + p3[2][2] + p3[3][2] + b_ih[col + 2 * H];
                const float r = 1.f / (1.f + expf(-(ir + cload(&gh[col]))));
                const float z = 1.f / (1.f + expf(-(iz + cload(&gh[col + H]))));
                const float n = tanhf(in_ + r * cload(&gh[col + 2 * H]));
                const float hnew = (1.f - z) * n + z * hidden[col];
                out[col] = hnew;
                out[H + col] = hnew;
            }
            __syncthreads();
        }
    }
}

extern "C" void kernel_launch(void* const* d_in, const int* in_sizes, int n_in,
                              void* d_out, int out_size, void* d_ws, size_t ws_size,
                              hipStream_t stream)
{
    const float* input  = (const float*)d_in[0];
    const float* hidden = (const float*)d_in[1];
    const float* enc    = (const float*)d_in[2];
    const float* attn_W = (const float*)d_in[3];
    const float* attn_b = (const float*)d_in[4];
    const float* comb_W = (const float*)d_in[5];
    const float* comb_b = (const float*)d_in[6];
    const float* w_ih   = (const float*)d_in[7];
    const float* w_hh   = (const float*)d_in[8];
    const float* b_ih   = (const float*)d_in[9];
    const float* b_hh   = (const float*)d_in[10];
    float* out = (float*)d_out;
    float* ws  = (float*)d_ws;

    // counters (16 KB) + flags must start zeroed
    hipMemsetAsync(ws + OFF_CNT, 0, 16384 + 512, stream);

    fused_decoder<<<NB, 256, 0, stream>>>(
        input, hidden, enc, attn_W, attn_b, comb_W, comb_b,
        w_ih, w_hh, b_ih, b_hh, out, ws);
}

// Round 13
// 36.275 us; speedup vs baseline: 1.3652x; 1.2555x over previous
//
#include <hip/hip_runtime.h>
#include <math.h>

#define H 2048
#define L 350
#define GH1 4096         // gh rows computed in K1; rest (2048) in K2

__device__ __forceinline__ float dot4(float4 a, float4 b, float acc) {
    acc = fmaf(a.x, b.x, acc);
    acc = fmaf(a.y, b.y, acc);
    acc = fmaf(a.z, b.z, acc);
    acc = fmaf(a.w, b.w, acc);
    return acc;
}

__device__ __forceinline__ float wsum(float v) {
    #pragma unroll
    for (int m = 1; m < 64; m <<= 1) v += __shfl_xor(v, m, 64);
    return v;
}
__device__ __forceinline__ float wmax(float v) {
    #pragma unroll
    for (int m = 1; m < 64; m <<= 1) v = fmaxf(v, __shfl_xor(v, m, 64));
    return v;
}

// gh row: 8KB row, one wave, 4 independent accumulator chains (4 loads in flight)
__device__ __forceinline__ void gh_row(int row, int lane,
    const float4* h4, const float* w_hh, const float* b_hh, float* gh)
{
    const float4* Wr = reinterpret_cast<const float4*>(w_hh + (size_t)row * H);
    float a0 = 0.f, a1 = 0.f, a2 = 0.f, a3 = 0.f;
    #pragma unroll
    for (int k = 0; k < 8; k += 4) {
        a0 = dot4(Wr[lane + (k + 0) * 64], h4[lane + (k + 0) * 64], a0);
        a1 = dot4(Wr[lane + (k + 1) * 64], h4[lane + (k + 1) * 64], a1);
        a2 = dot4(Wr[lane + (k + 2) * 64], h4[lane + (k + 2) * 64], a2);
        a3 = dot4(Wr[lane + (k + 3) * 64], h4[lane + (k + 3) * 64], a3);
    }
    const float acc = wsum((a0 + a1) + (a2 + a3));
    if (lane == 0) gh[row] = acc + b_hh[row];
}

// K1: waves 0..349: attn logits (16KB rows, 4-acc ILP); waves 350..: gh [0,GH1)
__global__ __launch_bounds__(256) void k1_logits_gh(
    const float* __restrict__ input, const float* __restrict__ hidden,
    const float* __restrict__ attn_W, const float* __restrict__ attn_b,
    const float* __restrict__ w_hh, const float* __restrict__ b_hh,
    float* __restrict__ logits, float* __restrict__ gh)
{
    const int w = threadIdx.x >> 6, lane = threadIdx.x & 63;
    const int item = blockIdx.x * 4 + w;
    const float4* x4 = reinterpret_cast<const float4*>(input);
    const float4* h4 = reinterpret_cast<const float4*>(hidden);
    if (item < L) {
        const float4* Wr = reinterpret_cast<const float4*>(attn_W + (size_t)item * (2 * H));
        float a0 = 0.f, a1 = 0.f, a2 = 0.f, a3 = 0.f;
        #pragma unroll
        for (int k = 0; k < 8; k += 4) {
            a0 = dot4(Wr[lane + (k + 0) * 64], x4[lane + (k + 0) * 64], a0);
            a1 = dot4(Wr[lane + (k + 1) * 64], x4[lane + (k + 1) * 64], a1);
            a2 = dot4(Wr[lane + (k + 2) * 64], x4[lane + (k + 2) * 64], a2);
            a3 = dot4(Wr[lane + (k + 3) * 64], x4[lane + (k + 3) * 64], a3);
        }
        #pragma unroll
        for (int k = 0; k < 8; k += 4) {
            a0 = dot4(Wr[512 + lane + (k + 0) * 64], h4[lane + (k + 0) * 64], a0);
            a1 = dot4(Wr[512 + lane + (k + 1) * 64], h4[lane + (k + 1) * 64], a1);
            a2 = dot4(Wr[512 + lane + (k + 2) * 64], h4[lane + (k + 2) * 64], a2);
            a3 = dot4(Wr[512 + lane + (k + 3) * 64], h4[lane + (k + 3) * 64], a3);
        }
        const float acc = wsum((a0 + a1) + (a2 + a3));
        if (lane == 0) logits[item] = acc + attn_b[item];
    } else if (item < L + GH1) {
        gh_row(item - L, lane, h4, w_hh, b_hh, gh);
    }
}

// K2: blocks 0..63: softmax (redundant per block, deterministic) + 32 ctx cols;
//     blocks 64..575: gh rows [GH1, 6144)
__global__ __launch_bounds__(256) void k2_softmax_ctx_gh(
    const float* __restrict__ logits, const float* __restrict__ enc,
    const float* __restrict__ hidden,
    const float* __restrict__ w_hh, const float* __restrict__ b_hh,
    float* __restrict__ ctx, float* __restrict__ gh, float* __restrict__ attn_out)
{
    const int t = threadIdx.x, w = t >> 6, lane = t & 63;
    if (blockIdx.x >= 64) {
        const int row = GH1 + (blockIdx.x - 64) * 4 + w;
        gh_row(row, lane, reinterpret_cast<const float4*>(hidden), w_hh, b_hh, gh);
        return;
    }
    __shared__ float attn_s[L];
    __shared__ float smax[4], ssum[4];
    __shared__ float partial[8][32];

    float v0 = (t < L) ? logits[t] : -INFINITY;
    float v1 = (t + 256 < L) ? logits[t + 256] : -INFINITY;
    float m = wmax(fmaxf(v0, v1));
    if (lane == 0) smax[w] = m;
    __syncthreads();
    m = fmaxf(fmaxf(smax[0], smax[1]), fmaxf(smax[2], smax[3]));
    float e0 = (t < L) ? expf(v0 - m) : 0.f;
    float e1 = (t + 256 < L) ? expf(v1 - m) : 0.f;
    float s = wsum(e0 + e1);
    if (lane == 0) ssum[w] = s;
    __syncthreads();
    const float inv = 1.f / (ssum[0] + ssum[1] + ssum[2] + ssum[3]);
    if (t < L) attn_s[t] = e0 * inv;
    if (t + 256 < L) attn_s[t + 256] = e1 * inv;
    if (blockIdx.x == 0) {
        if (t < L) attn_out[t] = e0 * inv;
        if (t + 256 < L) attn_out[t + 256] = e1 * inv;
    }
    __syncthreads();

    // ctx: col = blockIdx*32 + (t&31); 8-way row split (k = t>>5), 4-deep ILP
    const int col_l = t & 31, k = t >> 5;
    const int col = blockIdx.x * 32 + col_l;
    const float* ec = enc + col;
    float a0 = 0.f, a1 = 0.f, a2 = 0.f, a3 = 0.f;
    int j = k;
    for (; j + 24 < L; j += 32) {
        a0 = fmaf(attn_s[j],      ec[(size_t)j * H],        a0);
        a1 = fmaf(attn_s[j + 8],  ec[(size_t)(j + 8) * H],  a1);
        a2 = fmaf(attn_s[j + 16], ec[(size_t)(j + 16) * H], a2);
        a3 = fmaf(attn_s[j + 24], ec[(size_t)(j + 24) * H], a3);
    }
    for (; j < L; j += 8) a0 = fmaf(attn_s[j], ec[(size_t)j * H], a0);
    partial[k][col_l] = (a0 + a1) + (a2 + a3);
    __syncthreads();
    if (t < 32) {
        float acc = 0.f;
        #pragma unroll
        for (int kk = 0; kk < 8; ++kk) acc += partial[kk][t];
        ctx[blockIdx.x * 32 + t] = acc;
    }
}

// K3: one block per combine row. 256 threads x 4 float4 (independent) = row.
__global__ __launch_bounds__(256) void k3_combine(
    const float* __restrict__ input, const float* __restrict__ ctx,
    const float* __restrict__ comb_W, const float* __restrict__ comb_b,
    float* __restrict__ g)
{
    __shared__ float red[4];
    const int t = threadIdx.x, wv = t >> 6, lane = t & 63;
    const int r = blockIdx.x;
    const float4* x4 = reinterpret_cast<const float4*>(input);
    const float4* c4 = reinterpret_cast<const float4*>(ctx);
    const float4* Wr = reinterpret_cast<const float4*>(comb_W + (size_t)r * (2 * H));
    float a0 = dot4(Wr[t],       x4[t],       0.f);
    float a1 = dot4(Wr[t + 256], x4[t + 256], 0.f);
    float a2 = dot4(Wr[t + 512], c4[t],       0.f);
    float a3 = dot4(Wr[t + 768], c4[t + 256], 0.f);
    float acc = wsum((a0 + a1) + (a2 + a3));
    if (lane == 0) red[wv] = acc;
    __syncthreads();
    if (t == 0)
        g[r] = fmaxf(red[0] + red[1] + red[2] + red[3] + comb_b[r], 0.f);
}

// K4: one block per GRU column. 3 w_ih rows (8KB each, 6 indep loads) + gates.
__global__ __launch_bounds__(256) void k4_gru(
    const float* __restrict__ g, const float* __restrict__ hidden,
    const float* __restrict__ w_ih, const float* __restrict__ b_ih,
    const float* __restrict__ gh, float* __restrict__ out)
{
    __shared__ float part[4][3];
    const int t = threadIdx.x, wv = t >> 6, lane = t & 63;
    const int c = blockIdx.x;
    const float4* g4  = reinterpret_cast<const float4*>(g);
    const float4* W0 = reinterpret_cast<const float4*>(w_ih + (size_t)c * H);
    const float4* W1 = reinterpret_cast<const float4*>(w_ih + (size_t)(c + H) * H);
    const float4* W2 = reinterpret_cast<const float4*>(w_ih + (size_t)(c + 2 * H) * H);
    const float4 gv0 = g4[t], gv1 = g4[t + 256];
    float ar = dot4(W0[t], gv0, 0.f); ar = dot4(W0[t + 256], gv1, ar);
    float az = dot4(W1[t], gv0, 0.f); az = dot4(W1[t + 256], gv1, az);
    float an = dot4(W2[t], gv0, 0.f); an = dot4(W2[t + 256], gv1, an);
    ar = wsum(ar); az = wsum(az); an = wsum(an);
    if (lane == 0) { part[wv][0] = ar; part[wv][1] = az; part[wv][2] = an; }
    __syncthreads();
    if (t == 0) {
        const float ir  = part[0][0] + part[1][0] + part[2][0] + part[3][0] + b_ih[c];
        const float iz  = part[0][1] + part[1][1] + part[2][1] + part[3][1] + b_ih[c + H];
        const float in_ = part[0][2] + part[1][2] + part[2][2] + part[3][2] + b_ih[c + 2 * H];
        const float r = 1.f / (1.f + expf(-(ir + gh[c])));
        const float z = 1.f / (1.f + expf(-(iz + gh[c + H])));
        const float n = tanhf(in_ + r * gh[c + 2 * H]);
        const float hnew = (1.f - z) * n + z * hidden[c];
        out[c] = hnew;
        out[H + c] = hnew;
    }
}

extern "C" void kernel_launch(void* const* d_in, const int* in_sizes, int n_in,
                              void* d_out, int out_size, void* d_ws, size_t ws_size,
                              hipStream_t stream)
{
    const float* input  = (const float*)d_in[0];
    const float* hidden = (const float*)d_in[1];
    const float* enc    = (const float*)d_in[2];
    const float* attn_W = (const float*)d_in[3];
    const float* attn_b = (const float*)d_in[4];
    const float* comb_W = (const float*)d_in[5];
    const float* comb_b = (const float*)d_in[6];
    const float* w_ih   = (const float*)d_in[7];
    const float* w_hh   = (const float*)d_in[8];
    const float* b_ih   = (const float*)d_in[9];
    const float* b_hh   = (const float*)d_in[10];
    float* out = (float*)d_out;
    float* ws  = (float*)d_ws;

    float* logits = ws;            // 350
    float* gh     = ws + 512;      // 6144
    float* g      = ws + 7168;     // 2048
    float* ctx    = ws + 9216;     // 2048

    k1_logits_gh<<<(L + GH1 + 3) / 4, 256, 0, stream>>>(
        input, hidden, attn_W, attn_b, w_hh, b_hh, logits, gh);
    k2_softmax_ctx_gh<<<64 + (3 * H - GH1) / 4, 256, 0, stream>>>(
        logits, enc, hidden, w_hh, b_hh, ctx, gh, out + 2 * H);
    k3_combine<<<H, 256, 0, stream>>>(input, ctx, comb_W, comb_b, g);
    k4_gru<<<H, 256, 0, stream>>>(g, hidden, w_ih, b_ih, gh, out);
}

// Round 14
// 32.113 us; speedup vs baseline: 1.5421x; 1.1296x over previous
//
#include <hip/hip_runtime.h>
#include <math.h>

#define H 2048
#define L 350
#define NB 1024
#define NREP 16
#define MAGIC 0x7FC0FFEEu
#define BOUND 65536

// block roles
#define LOG_B0 0      // 88 logit blocks
#define CTX_B0 88     // 64 ctx blocks (88..151); watchers = 88..119
#define GHB_B0 152    // 872 gh blocks (152..1023)

// ws float offsets
#define OFF_GH   512
#define OFF_CTXR 8192        // 16 x 2048
#define OFF_GR   40960       // 16 x 2048
#define OFF_MK   73728       // uint marker area

// marker slot layout (uints, 16-uint = 64B spacing)
#define SLOTA 0              // 88
#define SLOTB (88*16)        // 64
#define SLOTC (SLOTB+64*16)  // 912 (872 gh blocks + 40 logit blocks)
#define SLOTG (SLOTC+912*16) // 1024
#define SUPC  (SLOTG+1024*16) // 32
#define SUPG  (SUPC+32*16)    // 32

#define VMCNT0() asm volatile("s_waitcnt vmcnt(0)" ::: "memory")

__device__ __forceinline__ float cload(const float* p) {
    return __hip_atomic_load(p, __ATOMIC_RELAXED, __HIP_MEMORY_SCOPE_AGENT);
}
__device__ __forceinline__ void cstore(float* p, float v) {
    __hip_atomic_store(p, v, __ATOMIC_RELAXED, __HIP_MEMORY_SCOPE_AGENT);
}
__device__ __forceinline__ unsigned long long cload64(const unsigned long long* p) {
    return __hip_atomic_load(p, __ATOMIC_RELAXED, __HIP_MEMORY_SCOPE_AGENT);
}
__device__ __forceinline__ void postmk(unsigned* p) {
    __hip_atomic_store(p, MAGIC, __ATOMIC_RELAXED, __HIP_MEMORY_SCOPE_SYSTEM);
}
__device__ __forceinline__ unsigned peekmk(const unsigned* p) {
    return __hip_atomic_load(p, __ATOMIC_RELAXED, __HIP_MEMORY_SCOPE_SYSTEM);
}
// each of first n threads polls one slot; all threads join the barrier
__device__ __forceinline__ void waitslots(const unsigned* base, int n) {
    const int t = threadIdx.x;
    for (int s = t; s < n; s += 256)
        for (int it = 0; it < BOUND; ++it) {
            if (peekmk(&base[s * 16]) == MAGIC) break;
            __builtin_amdgcn_s_sleep(8);
        }
    __syncthreads();
}

__device__ __forceinline__ float dot4(float4 a, float4 b, float acc) {
    acc = fmaf(a.x, b.x, acc);
    acc = fmaf(a.y, b.y, acc);
    acc = fmaf(a.z, b.z, acc);
    acc = fmaf(a.w, b.w, acc);
    return acc;
}
__device__ __forceinline__ float wsum(float v) {
    #pragma unroll
    for (int m = 1; m < 64; m <<= 1) v += __shfl_xor(v, m, 64);
    return v;
}
__device__ __forceinline__ float wmax(float v) {
    #pragma unroll
    for (int m = 1; m < 64; m <<= 1) v = fmaxf(v, __shfl_xor(v, m, 64));
    return v;
}

__device__ __forceinline__ void gh_row(int row, int lane,
    const float4* h4, const float* w_hh, const float* b_hh, float* gh)
{
    const float4* Wr = reinterpret_cast<const float4*>(w_hh + (size_t)row * H);
    float a0 = 0.f, a1 = 0.f, a2 = 0.f, a3 = 0.f;
    #pragma unroll
    for (int k = 0; k < 8; k += 4) {
        a0 = dot4(Wr[lane + (k + 0) * 64], h4[lane + (k + 0) * 64], a0);
        a1 = dot4(Wr[lane + (k + 1) * 64], h4[lane + (k + 1) * 64], a1);
        a2 = dot4(Wr[lane + (k + 2) * 64], h4[lane + (k + 2) * 64], a2);
        a3 = dot4(Wr[lane + (k + 3) * 64], h4[lane + (k + 3) * 64], a3);
    }
    const float acc = wsum((a0 + a1) + (a2 + a3));
    if (lane == 0) cstore(&gh[row], acc + b_hh[row]);
}

__global__ __launch_bounds__(256, 4) void fused_decoder(
    const float* __restrict__ input, const float* __restrict__ hidden,
    const float* __restrict__ enc,
    const float* __restrict__ attn_W, const float* __restrict__ attn_b,
    const float* __restrict__ comb_W, const float* __restrict__ comb_b,
    const float* __restrict__ w_ih, const float* __restrict__ w_hh,
    const float* __restrict__ b_ih, const float* __restrict__ b_hh,
    float* __restrict__ out, float* __restrict__ ws)
{
    __shared__ __align__(16) float sh[2048];
    __shared__ float smax[4], ssum[4];
    __shared__ float part[8][32];
    __shared__ float red[4];
    __shared__ float p3[4][3];

    float* logits = ws;
    float* gh     = ws + OFF_GH;
    float* ctxrep = ws + OFF_CTXR;
    float* grep   = ws + OFF_GR;
    unsigned* mk  = (unsigned*)(ws + OFF_MK);

    const int b = blockIdx.x, tid = threadIdx.x;
    const int wv = tid >> 6, lane = tid & 63;
    const float4* x4 = reinterpret_cast<const float4*>(input);
    const float4* h4 = reinterpret_cast<const float4*>(hidden);

    // ======================= phase 1 =======================
    if (b < CTX_B0) {
        // ---- logits: 1 row/wave, items b*4+wv ----
        const int r = b * 4 + wv;
        if (r < L) {
            const float4* Wr = reinterpret_cast<const float4*>(attn_W + (size_t)r * (2 * H));
            float a0 = 0.f, a1 = 0.f, a2 = 0.f, a3 = 0.f;
            #pragma unroll
            for (int k = 0; k < 8; k += 4) {
                a0 = dot4(Wr[lane + (k+0)*64], x4[lane + (k+0)*64], a0);
                a1 = dot4(Wr[lane + (k+1)*64], x4[lane + (k+1)*64], a1);
                a2 = dot4(Wr[lane + (k+2)*64], x4[lane + (k+2)*64], a2);
                a3 = dot4(Wr[lane + (k+3)*64], x4[lane + (k+3)*64], a3);
            }
            #pragma unroll
            for (int k = 0; k < 8; k += 4) {
                a0 = dot4(Wr[512 + lane + (k+0)*64], h4[lane + (k+0)*64], a0);
                a1 = dot4(Wr[512 + lane + (k+1)*64], h4[lane + (k+1)*64], a1);
                a2 = dot4(Wr[512 + lane + (k+2)*64], h4[lane + (k+2)*64], a2);
                a3 = dot4(Wr[512 + lane + (k+3)*64], h4[lane + (k+3)*64], a3);
            }
            const float acc = wsum((a0 + a1) + (a2 + a3));
            if (lane == 0) cstore(&logits[r], acc + attn_b[r]);
        }
        VMCNT0();
        __syncthreads();
        if (tid == 0) postmk(&mk[SLOTA + b * 16]);
        // tail gh rows 6104..6143 on blocks 0..39 (wave 0 does it)
        if (b < 40) {
            if (wv == 0) gh_row(6104 + b, lane, h4, w_hh, b_hh, gh);
            VMCNT0();
            __syncthreads();
            if (tid == 0) postmk(&mk[SLOTC + (872 + b) * 16]);
        }
    } else if (b < GHB_B0) {
        // ---- ctx blocks: wait logits, softmax, 32 ctx cols ----
        const int cb = b - CTX_B0;
        waitslots(&mk[SLOTA], 88);
        float v0 = (tid < L) ? cload(&logits[tid]) : -INFINITY;
        float v1 = (tid + 256 < L) ? cload(&logits[tid + 256]) : -INFINITY;
        float m = wmax(fmaxf(v0, v1));
        if (lane == 0) smax[wv] = m;
        __syncthreads();
        m = fmaxf(fmaxf(smax[0], smax[1]), fmaxf(smax[2], smax[3]));
        float e0 = (tid < L) ? expf(v0 - m) : 0.f;
        float e1 = (tid + 256 < L) ? expf(v1 - m) : 0.f;
        float s = wsum(e0 + e1);
        if (lane == 0) ssum[wv] = s;
        __syncthreads();
        const float inv = 1.f / (ssum[0] + ssum[1] + ssum[2] + ssum[3]);
        if (tid < L) sh[tid] = e0 * inv;
        if (tid + 256 < L) sh[tid + 256] = e1 * inv;
        if (cb == 0) {
            if (tid < L) out[2 * H + tid] = e0 * inv;
            if (tid + 256 < L) out[2 * H + tid + 256] = e1 * inv;
        }
        __syncthreads();
        const int col_l = tid & 31, k = tid >> 5;
        const float* ec = enc + cb * 32 + col_l;
        float a0 = 0.f, a1 = 0.f, a2 = 0.f, a3 = 0.f;
        int j = k;
        for (; j + 24 < L; j += 32) {
            a0 = fmaf(sh[j],      ec[(size_t)j * H],        a0);
            a1 = fmaf(sh[j + 8],  ec[(size_t)(j + 8) * H],  a1);
            a2 = fmaf(sh[j + 16], ec[(size_t)(j + 16) * H], a2);
            a3 = fmaf(sh[j + 24], ec[(size_t)(j + 24) * H], a3);
        }
        for (; j < L; j += 8) a0 = fmaf(sh[j], ec[(size_t)j * H], a0);
        part[k][col_l] = (a0 + a1) + (a2 + a3);
        __syncthreads();
        if (tid < 32) {
            const float acc = part[0][tid] + part[1][tid] + part[2][tid] + part[3][tid]
                            + part[4][tid] + part[5][tid] + part[6][tid] + part[7][tid];
            #pragma unroll
            for (int rp = 0; rp < NREP; ++rp)
                cstore(&ctxrep[rp * 2048 + cb * 32 + tid], acc);
        }
        VMCNT0();
        __syncthreads();
        if (tid == 0) postmk(&mk[SLOTB + cb * 16]);
    } else {
        // ---- gh blocks: 7 rows each, rows m*7+j ----
        const int m = b - GHB_B0;
        #pragma unroll
        for (int j = 0; j < 7; ++j)
            if ((j & 3) == wv) gh_row(m * 7 + j, lane, h4, w_hh, b_hh, gh);
        VMCNT0();
        __syncthreads();
        if (tid == 0) postmk(&mk[SLOTC + m * 16]);
    }

    // ======================= phase 2: combine (all blocks, 2 rows) =========
    waitslots(&mk[SLOTB], 64);
    {
        unsigned long long* sh64 = reinterpret_cast<unsigned long long*>(sh);
        const unsigned long long* c64 =
            reinterpret_cast<const unsigned long long*>(ctxrep + (b & (NREP - 1)) * 2048);
        for (int i = tid; i < H / 2; i += 256) sh64[i] = cload64(&c64[i]);
    }
    __syncthreads();
    {
        const float4* c4 = reinterpret_cast<const float4*>(sh);
        #pragma unroll
        for (int rr = 0; rr < 2; ++rr) {
            const int r = b * 2 + rr;
            const float4* Wr = reinterpret_cast<const float4*>(comb_W + (size_t)r * (2 * H));
            float a0 = dot4(Wr[tid],       x4[tid],       0.f);
            float a1 = dot4(Wr[tid + 256], x4[tid + 256], 0.f);
            float a2 = dot4(Wr[tid + 512], c4[tid],       0.f);
            float a3 = dot4(Wr[tid + 768], c4[tid + 256], 0.f);
            const float acc = wsum((a0 + a1) + (a2 + a3));
            if (lane == 0) red[wv] = acc;
            __syncthreads();
            if (tid == 0) {
                const float gval = fmaxf(red[0] + red[1] + red[2] + red[3] + comb_b[r], 0.f);
                #pragma unroll
                for (int rp = 0; rp < NREP; ++rp) cstore(&grep[rp * 2048 + r], gval);
            }
            __syncthreads();
        }
    }
    VMCNT0();
    if (tid == 0) postmk(&mk[SLOTG + b * 16]);

    // ======================= watchers: aggregate slotC + slotG =============
    if (b >= 88 && b < 120) {
        const int w = b - 88;
        const int cfrom = w * 29, cto = (cfrom + 29 < 912) ? cfrom + 29 : 912;
        if (tid < cto - cfrom) {
            for (int it = 0; it < BOUND; ++it) {
                if (peekmk(&mk[SLOTC + (cfrom + tid) * 16]) == MAGIC) break;
                __builtin_amdgcn_s_sleep(8);
            }
        } else if (tid >= 64 && tid < 96) {
            for (int it = 0; it < BOUND; ++it) {
                if (peekmk(&mk[SLOTG + (w * 32 + tid - 64) * 16]) == MAGIC) break;
                __builtin_amdgcn_s_sleep(8);
            }
        }
        __syncthreads();
        if (tid == 0) { postmk(&mk[SUPC + w * 16]); postmk(&mk[SUPG + w * 16]); }
    }

    // ======================= phase 3: GRU (all blocks, 2 cols) =============
    {
        const int t = tid;
        if (t < 32) {
            for (int it = 0; it < BOUND; ++it) {
                if (peekmk(&mk[SUPC + t * 16]) == MAGIC) break;
                __builtin_amdgcn_s_sleep(8);
            }
        } else if (t >= 64 && t < 96) {
            for (int it = 0; it < BOUND; ++it) {
                if (peekmk(&mk[SUPG + (t - 64) * 16]) == MAGIC) break;
                __builtin_amdgcn_s_sleep(8);
            }
        }
        __syncthreads();
    }
    {
        unsigned long long* sh64 = reinterpret_cast<unsigned long long*>(sh);
        const unsigned long long* g64 =
            reinterpret_cast<const unsigned long long*>(grep + (b & (NREP - 1)) * 2048);
        for (int i = tid; i < H / 2; i += 256) sh64[i] = cload64(&g64[i]);
    }
    __syncthreads();
    {
        const float4* g4 = reinterpret_cast<const float4*>(sh);
        #pragma unroll
        for (int cc = 0; cc < 2; ++cc) {
            const int col = b * 2 + cc;
            const float4* W0 = reinterpret_cast<const float4*>(w_ih + (size_t)col * H);
            const float4* W1 = reinterpret_cast<const float4*>(w_ih + (size_t)(col + H) * H);
            const float4* W2 = reinterpret_cast<const float4*>(w_ih + (size_t)(col + 2 * H) * H);
            const float4 gv0 = g4[tid], gv1 = g4[tid + 256];
            float ar = dot4(W0[tid], gv0, 0.f); ar = dot4(W0[tid + 256], gv1, ar);
            float az = dot4(W1[tid], gv0, 0.f); az = dot4(W1[tid + 256], gv1, az);
            float an = dot4(W2[tid], gv0, 0.f); an = dot4(W2[tid + 256], gv1, an);
            ar = wsum(ar); az = wsum(az); an = wsum(an);
            if (lane == 0) { p3[wv][0] = ar; p3[wv][1] = az; p3[wv][2] = an; }
            __syncthreads();
            if (tid == 0) {
                const float ir  = p3[0][0] + p3[1][0] + p3[2][0] + p3[3][0] + b_ih[col];
                const float iz  = p3[0][1] + p3[1][1] + p3[2][1] + p3[3][1] + b_ih[col + H];
                const float in_ = p3[0][2] + p3[1][2] + p3[2][2] + p3[3][2] + b_ih[col + 2 * H];
                const float r = 1.f / (1.f + expf(-(ir + cload(&gh[col]))));
                const float z = 1.f / (1.f + expf(-(iz + cload(&gh[col + H]))));
                const float n = tanhf(in_ + r * cload(&gh[col + 2 * H]));
                const float hnew = (1.f - z) * n + z * hidden[col];
                out[col] = hnew;
                out[H + col] = hnew;
            }
            __syncthreads();
        }
    }
}

extern "C" void kernel_launch(void* const* d_in, const int* in_sizes, int n_in,
                              void* d_out, int out_size, void* d_ws, size_t ws_size,
                              hipStream_t stream)
{
    const float* input  = (const float*)d_in[0];
    const float* hidden = (const float*)d_in[1];
    const float* enc    = (const float*)d_in[2];
    const float* attn_W = (const float*)d_in[3];
    const float* attn_b = (const float*)d_in[4];
    const float* comb_W = (const float*)d_in[5];
    const float* comb_b = (const float*)d_in[6];
    const float* w_ih   = (const float*)d_in[7];
    const float* w_hh   = (const float*)d_in[8];
    const float* b_ih   = (const float*)d_in[9];
    const float* b_hh   = (const float*)d_in[10];
    float* out = (float*)d_out;
    float* ws  = (float*)d_ws;

    fused_decoder<<<NB, 256, 0, stream>>>(
        input, hidden, enc, attn_W, attn_b, comb_W, comb_b,
        w_ih, w_hh, b_ih, b_hh, out, ws);
}